// Round 3
// baseline (10600.000 us; speedup 1.0000x reference)
//
#include <hip/hip_runtime.h>
#include <hip/hip_bf16.h>

// Bidirectional LSTM w/ field gates. B=128,T=256,I=H=1024,F=64.
// I/O is FP32 (per reference dtypes). Round 3: pre-convert inputs/weights to
// bf16 in ws, per-step MFMA kernels (256 graph nodes), fp32 out.

#define Bn 128
#define Tn 256
#define In 1024
#define Hn 1024
#define Fn 64

typedef __attribute__((ext_vector_type(8))) short short8;
typedef __attribute__((ext_vector_type(4))) short short4v;
typedef __attribute__((ext_vector_type(4))) float f32x4;

__device__ __forceinline__ unsigned short f2bf(float f) {
  __hip_bfloat16 h = __float2bfloat16(f);
  return *reinterpret_cast<unsigned short*>(&h);
}
__device__ __forceinline__ float sigm(float x) { return 1.0f / (1.0f + __expf(-x)); }
__device__ __forceinline__ float tanh_(float x) { return 1.0f - 2.0f / (1.0f + __expf(2.0f * x)); }

__global__ void f32_to_bf16_vec(const float* __restrict__ src, short* __restrict__ dst, int n4) {
  for (int i = blockIdx.x * blockDim.x + threadIdx.x; i < n4; i += gridDim.x * blockDim.x) {
    const float4 v = ((const float4*)src)[i];
    short4v o;
    o[0] = (short)f2bf(v.x); o[1] = (short)f2bf(v.y);
    o[2] = (short)f2bf(v.z); o[3] = (short)f2bf(v.w);
    ((short4v*)dst)[i] = o;
  }
}

__global__ void init_state(float* __restrict__ c_state, unsigned int* __restrict__ h0w) {
  const int i = blockIdx.x * blockDim.x + threadIdx.x;
  if (i < 2 * Bn * Hn) c_state[i] = 0.0f;
  if (i < (2 * Bn * Hn) / 2) h0w[i] = 0u;  // zero bf16 h buffer 0
}

// grid: (64 unit-tiles, 2 m-tiles, 2 dirs); block 256 threads (4 waves).
// Block tile: 64 batches x 16 hidden units (= 64 gate cols, frag nf <-> gate nf).
// Wave w: batch rows m0+16w .. +15, all 4 gate frags.
__global__ __launch_bounds__(256) void lstm_step(
    const short* __restrict__ seq, const short* __restrict__ fpos,   // bf16 (ws)
    const short* __restrict__ Wih_f, const short* __restrict__ Whh_f,
    const short* __restrict__ Wfp_f,
    const short* __restrict__ Wih_b, const short* __restrict__ Whh_b,
    const short* __restrict__ Wfp_b,                                  // bf16 (ws)
    const float* __restrict__ b_f,  const float* __restrict__ bfp_f,  // fp32
    const float* __restrict__ b_b,  const float* __restrict__ bfp_b,
    float* __restrict__ c_state,
    const short* __restrict__ h_read, short* __restrict__ h_write,
    float* __restrict__ out, int s)
{
  const int utile = blockIdx.x;
  const int mtile = blockIdx.y;
  const int dir   = blockIdx.z;
  const int t = dir ? (Tn - 1 - s) : s;
  const int j0 = utile * 16, m0 = mtile * 64;
  const int tid = threadIdx.x;
  const int lane = tid & 63, w = tid >> 6;
  const int l15 = lane & 15, lk = lane >> 4;

  const short* Wih = dir ? Wih_b : Wih_f;
  const short* Whh = dir ? Whh_b : Whh_f;
  const short* Wfp = dir ? Wfp_b : Wfp_f;
  const float* bg  = dir ? b_b   : b_f;
  const float* bfp = dir ? bfp_b : bfp_f;

  // ---- main gate GEMM: [64 x 64cols], K = I (x part) + H (h part) ----
  const int abat = m0 + 16 * w + l15;                      // A row = batch
  const short* xrow = seq    + ((size_t)abat * Tn + t) * In + lk * 8;
  const short* hrow = h_read + ((size_t)dir * Bn + abat) * Hn + lk * 8;

  f32x4 acc[4];
#pragma unroll
  for (int nf = 0; nf < 4; ++nf) acc[nf] = (f32x4){0.f, 0.f, 0.f, 0.f};

  const short* wr_ih[4];
  const short* wr_hh[4];
#pragma unroll
  for (int nf = 0; nf < 4; ++nf) {
    const int row = nf * Hn + j0 + l15;                    // gate nf, unit j0+l15
    wr_ih[nf] = Wih + (size_t)row * In + lk * 8;
    wr_hh[nf] = Whh + (size_t)row * Hn + lk * 8;
  }

  for (int k = 0; k < In; k += 32) {
    const short8 a = *(const short8*)(xrow + k);
#pragma unroll
    for (int nf = 0; nf < 4; ++nf) {
      const short8 b = *(const short8*)(wr_ih[nf] + k);
      acc[nf] = __builtin_amdgcn_mfma_f32_16x16x32_bf16(a, b, acc[nf], 0, 0, 0);
    }
  }
  for (int k = 0; k < Hn; k += 32) {
    const short8 a = *(const short8*)(hrow + k);
#pragma unroll
    for (int nf = 0; nf < 4; ++nf) {
      const short8 b = *(const short8*)(wr_hh[nf] + k);
      acc[nf] = __builtin_amdgcn_mfma_f32_16x16x32_bf16(a, b, acc[nf], 0, 0, 0);
    }
  }

  // ---- field-gate GEMM: [64 x 32], K = F. nf=0 -> l rows, nf=1 -> d rows ----
  f32x4 accf[2];
#pragma unroll
  for (int nf = 0; nf < 2; ++nf) accf[nf] = (f32x4){0.f, 0.f, 0.f, 0.f};
  const short* frow = fpos + ((size_t)abat * Tn + t) * Fn + lk * 8;
#pragma unroll
  for (int k = 0; k < Fn; k += 32) {
    const short8 a = *(const short8*)(frow + k);
#pragma unroll
    for (int nf = 0; nf < 2; ++nf) {
      const short8 b = *(const short8*)(Wfp + (size_t)(nf * Hn + j0 + l15) * Fn + lk * 8 + k);
      accf[nf] = __builtin_amdgcn_mfma_f32_16x16x32_bf16(a, b, accf[nf], 0, 0, 0);
    }
  }

  // ---- exchange gates via LDS (D: row=(lane>>4)*4+r -> batch, col=lane&15 -> unit) ----
  __shared__ float lds[4][64][17];
  __shared__ float ldsf[2][64][17];
#pragma unroll
  for (int nf = 0; nf < 4; ++nf)
#pragma unroll
    for (int r = 0; r < 4; ++r)
      lds[nf][16 * w + lk * 4 + r][l15] = acc[nf][r];
#pragma unroll
  for (int nf = 0; nf < 2; ++nf)
#pragma unroll
    for (int r = 0; r < 4; ++r)
      ldsf[nf][16 * w + lk * 4 + r][l15] = accf[nf][r];
  __syncthreads();

  // ---- pointwise update: 1024 (batch,unit) pairs, 4 per thread ----
  const size_t OUTN = (size_t)Tn * Bn * 2 * Hn;
#pragma unroll
  for (int q = 0; q < 4; ++q) {
    const int p = tid + 256 * q;
    const int ml = p >> 4, jl = p & 15;
    const int bat = m0 + ml, j = j0 + jl;
    const float i_g = sigm (lds[0][ml][jl] + bg[j]);
    const float f_g = sigm (lds[1][ml][jl] + bg[Hn + j]);
    const float g_g = tanh_(lds[2][ml][jl] + bg[2 * Hn + j]);
    const float o_g = sigm (lds[3][ml][jl] + bg[3 * Hn + j]);
    const float l_g = sigm (ldsf[0][ml][jl] + bfp[j]);
    const float d_g = tanh_(ldsf[1][ml][jl] + bfp[Hn + j]);
    const size_t cidx = ((size_t)dir * Bn + bat) * Hn + j;
    const float c_new = f_g * c_state[cidx] + i_g * g_g + l_g * d_g;
    const float h_new = o_g * tanh_(c_new);
    c_state[cidx] = c_new;
    h_write[cidx] = (short)f2bf(h_new);
    out[((size_t)t * Bn + bat) * (2 * Hn) + (size_t)dir * Hn + j] = h_new;
    if (s == Tn - 1) {
      out[OUTN + cidx] = h_new;                             // h_n [2,B,H]
      out[OUTN + (size_t)2 * Bn * Hn + cidx] = c_new;       // c_n [2,B,H]
    }
  }
}

static inline void conv(const void* src, short* dst, size_t n, hipStream_t stream) {
  int n4 = (int)(n / 4);
  int blocks = (n4 + 255) / 256; if (blocks > 8192) blocks = 8192;
  hipLaunchKernelGGL(f32_to_bf16_vec, dim3(blocks), dim3(256), 0, stream,
                     (const float*)src, dst, n4);
}

extern "C" void kernel_launch(void* const* d_in, const int* in_sizes, int n_in,
                              void* d_out, int out_size, void* d_ws, size_t ws_size,
                              hipStream_t stream) {
  (void)in_sizes; (void)n_in; (void)out_size; (void)ws_size;
  const float* b_f   = (const float*)d_in[4];
  const float* bfp_f = (const float*)d_in[6];
  const float* b_b   = (const float*)d_in[9];
  const float* bfp_b = (const float*)d_in[11];

  char* p = (char*)d_ws;
  float* c_state = (float*)p;            p += (size_t)2 * Bn * Hn * 4;
  short* h0      = (short*)p;            p += (size_t)2 * Bn * Hn * 2;
  short* h1      = (short*)p;            p += (size_t)2 * Bn * Hn * 2;
  short* seq_bf  = (short*)p;            p += (size_t)Bn * Tn * In * 2;
  short* fpos_bf = (short*)p;            p += (size_t)Bn * Tn * Fn * 2;
  short* Wih_bf[2], *Whh_bf[2], *Wfp_bf[2];
  for (int d = 0; d < 2; ++d) { Wih_bf[d] = (short*)p; p += (size_t)4 * Hn * In * 2; }
  for (int d = 0; d < 2; ++d) { Whh_bf[d] = (short*)p; p += (size_t)4 * Hn * Hn * 2; }
  for (int d = 0; d < 2; ++d) { Wfp_bf[d] = (short*)p; p += (size_t)2 * Hn * Fn * 2; }
  float* out = (float*)d_out;

  conv(d_in[0], seq_bf,   (size_t)Bn * Tn * In, stream);
  conv(d_in[1], fpos_bf,  (size_t)Bn * Tn * Fn, stream);
  conv(d_in[2], Wih_bf[0], (size_t)4 * Hn * In, stream);
  conv(d_in[3], Whh_bf[0], (size_t)4 * Hn * Hn, stream);
  conv(d_in[5], Wfp_bf[0], (size_t)2 * Hn * Fn, stream);
  conv(d_in[7], Wih_bf[1], (size_t)4 * Hn * In, stream);
  conv(d_in[8], Whh_bf[1], (size_t)4 * Hn * Hn, stream);
  conv(d_in[10], Wfp_bf[1], (size_t)2 * Hn * Fn, stream);

  hipLaunchKernelGGL(init_state, dim3((2 * Bn * Hn + 255) / 256), dim3(256), 0, stream,
                     c_state, (unsigned int*)h0);

  for (int s = 0; s < Tn; ++s) {
    const short* hr = (s & 1) ? h1 : h0;
    short* hw       = (s & 1) ? h0 : h1;
    hipLaunchKernelGGL(lstm_step, dim3(64, 2, 2), dim3(256), 0, stream,
                       seq_bf, fpos_bf,
                       Wih_bf[0], Whh_bf[0], Wfp_bf[0],
                       Wih_bf[1], Whh_bf[1], Wfp_bf[1],
                       b_f, bfp_f, b_b, bfp_b,
                       c_state, hr, hw, out, s);
  }
}